// Round 6
// baseline (1349.904 us; speedup 1.0000x reference)
//
#include <hip/hip_runtime.h>
#include <hip/hip_bf16.h>

#define Tn   8192
#define Dn   1024
#define FFn  4096
#define En   8
#define CAPn 2560
#define MAXROWS 16384  // <= K*T total kept slots

typedef __attribute__((ext_vector_type(8))) short bf16x8;
typedef __attribute__((ext_vector_type(4))) float f32x4;

__device__ inline ushort f2bf(float f) {            // RNE fp32->bf16 bits
  unsigned u = __float_as_uint(f);
  return (ushort)((u + 0x7fff + ((u >> 16) & 1)) >> 16);
}
__device__ inline float bf2f(ushort b) { return __uint_as_float(((unsigned)b) << 16); }

// split 8 fp32 -> hi (truncated) + lo bf16 planes; hi+lo exact to ~2^-17
__device__ inline void split8(const float* v, uint4& hq, uint4& lq) {
  union U8 { ushort u[8]; uint4 q; } H, L;
#pragma unroll
  for (int j = 0; j < 8; ++j) {
    const unsigned u = __float_as_uint(v[j]);
    H.u[j] = (ushort)(u >> 16);
    L.u[j] = (ushort)(__float_as_uint(v[j] - __uint_as_float(u & 0xffff0000u)) >> 16);
  }
  hq = H.q;
  lq = L.q;
}

// ---------------------------------------------------------------- gating ----
__global__ __launch_bounds__(256) void gate_kernel(
    const float* __restrict__ x, const float* __restrict__ gw,
    const float* __restrict__ gb, int* __restrict__ tidx,
    float* __restrict__ tprob) {
  __shared__ float sgw[En * Dn];  // 32 KB
  for (int i = threadIdx.x; i < En * Dn / 4; i += 256)
    ((float4*)sgw)[i] = ((const float4*)gw)[i];
  __syncthreads();
  const int wave = threadIdx.x >> 6, lane = threadIdx.x & 63;
  const int t = blockIdx.x * 4 + wave;
  float acc[En];
#pragma unroll
  for (int e = 0; e < En; ++e) acc[e] = 0.f;
  const float4* xr = (const float4*)(x + (size_t)t * Dn);
#pragma unroll
  for (int it = 0; it < Dn / 4 / 64; ++it) {
    const float4 xv = xr[it * 64 + lane];
#pragma unroll
    for (int e = 0; e < En; ++e) {
      const float4 wv = ((const float4*)(sgw + e * Dn))[it * 64 + lane];
      acc[e] += xv.x * wv.x + xv.y * wv.y + xv.z * wv.z + xv.w * wv.w;
    }
  }
#pragma unroll
  for (int e = 0; e < En; ++e)
#pragma unroll
    for (int off = 32; off; off >>= 1) acc[e] += __shfl_xor(acc[e], off, 64);
  if (lane == 0) {
    float lg[En], mx = -1e30f;
#pragma unroll
    for (int e = 0; e < En; ++e) { lg[e] = acc[e] + gb[e]; mx = fmaxf(mx, lg[e]); }
    float ex[En], s = 0.f;
#pragma unroll
    for (int e = 0; e < En; ++e) { ex[e] = expf(lg[e] - mx); s += ex[e]; }
    int i0 = 0;
#pragma unroll
    for (int e = 1; e < En; ++e) if (ex[e] > ex[i0]) i0 = e;
    int i1 = (i0 == 0) ? 1 : 0;
#pragma unroll
    for (int e = 0; e < En; ++e) if (e != i0 && ex[e] > ex[i1]) i1 = e;
    const float inv = 1.f / s;
    tidx[t * 2 + 0] = i0;  tidx[t * 2 + 1] = i1;
    tprob[t * 2 + 0] = ex[i0] * inv;  tprob[t * 2 + 1] = ex[i1] * inv;
  }
}

// ------------------------------------------------------- routing (1 block) --
__global__ __launch_bounds__(1024) void route_kernel(
    const int* __restrict__ tidx, const float* __restrict__ tprob,
    int* __restrict__ slot_token, float* __restrict__ slot_w,
    int* __restrict__ meta) {
  __shared__ int sc[1024][16];  // 64 KB
  const int tid = threadIdx.x;
  int cnt[16];
#pragma unroll
  for (int j = 0; j < 16; ++j) cnt[j] = 0;
  int eb[8][2];
#pragma unroll
  for (int i = 0; i < 8; ++i) {
    const int t = tid * 8 + i;
    eb[i][0] = tidx[t * 2 + 0];
    eb[i][1] = tidx[t * 2 + 1];
#pragma unroll
    for (int e = 0; e < 8; ++e) {
      cnt[e]     += (eb[i][0] == e);
      cnt[8 + e] += (eb[i][1] == e);
    }
  }
  int own[16];
#pragma unroll
  for (int j = 0; j < 16; ++j) { own[j] = cnt[j]; sc[tid][j] = cnt[j]; }
  __syncthreads();
  for (int off = 1; off < 1024; off <<= 1) {
    int nb[16];
    if (tid >= off) {
#pragma unroll
      for (int j = 0; j < 16; ++j) nb[j] = sc[tid - off][j];
    } else {
#pragma unroll
      for (int j = 0; j < 16; ++j) nb[j] = 0;
    }
    __syncthreads();
#pragma unroll
    for (int j = 0; j < 16; ++j) sc[tid][j] += nb[j];
    __syncthreads();
  }
  int tot[16], exc[16];
#pragma unroll
  for (int j = 0; j < 16; ++j) {
    tot[j] = sc[1023][j];
    exc[j] = sc[tid][j] - own[j];
  }
  __syncthreads();
  if (tid == 0) {
    int b = 0;
#pragma unroll
    for (int e = 0; e < 8; ++e) {
      const int c0 = min(tot[e], CAPn);
      const int c1 = min(tot[8 + e], CAPn);
      sc[0][e] = b;
      sc[1][e] = c0;
      meta[e] = c0 + c1;
      meta[8 + e] = b;
      b += c0 + c1;
    }
  }
  __syncthreads();
  int pos[16];
#pragma unroll
  for (int j = 0; j < 16; ++j) pos[j] = exc[j];
#pragma unroll
  for (int i = 0; i < 8; ++i) {
    const int t = tid * 8 + i;
#pragma unroll
    for (int c = 0; c < 2; ++c) {
      const int e = eb[i][c];
      const int jt = c * 8 + e;
      int p = 0;
#pragma unroll
      for (int j = 0; j < 16; ++j) p = (j == jt) ? pos[j] : p;
#pragma unroll
      for (int j = 0; j < 16; ++j) pos[j] += (j == jt) ? 1 : 0;
      if (p < CAPn) {
        const int slot = sc[0][e] + ((c == 1) ? sc[1][e] : 0) + p;
        slot_token[slot] = t;
        slot_w[slot] = tprob[t * 2 + c];
      }
    }
  }
}

// --------------------------------------------- split-bf16 MFMA FFN GEMMs ----
// GEMM==1: H[slot] = relu(X[token[slot]] @ W1[e] + b1[e])   (bf16 out)
// GEMM==2: y[token] += w * (H[slot] @ W2[e] + b2[e])         (fp32 atomics)
// BK=64; reg-staged with T14 prefetch (issue next tile's loads before MFMA).
// LDS planes [row][64 bf16], 16B block swizzle blk' = kb ^ (row&7):
// conflict-free ds_read_b128 fragments (32B/bank even), bijective per row.
template <int GEMM>
__global__ __launch_bounds__(256) void mfma_ffn(
    const float* __restrict__ Xf, const ushort* __restrict__ Hb,
    const float* __restrict__ Wg, const float* __restrict__ bias,
    const int* __restrict__ slot_token, const float* __restrict__ slot_w,
    const int* __restrict__ meta, ushort* __restrict__ Hout,
    float* __restrict__ y) {
  constexpr int Kd = (GEMM == 1) ? Dn : FFn;
  constexpr int Nd = (GEMM == 1) ? FFn : Dn;
  const int e = blockIdx.z;
  const int cnt = meta[e];
  const int m0 = blockIdx.y * 128;
  if (m0 >= cnt) return;
  const int base = meta[8 + e];
  const int n0 = blockIdx.x * 128;
  const float* We = Wg + (size_t)e * Kd * Nd;

  __shared__ ushort Ah[128 * 64];   // 16 KB each
  __shared__ ushort Al[128 * 64];   // dead (stripped) for GEMM2
  __shared__ ushort Bh[128 * 64];
  __shared__ ushort Bl[128 * 64];
  __shared__ int srow[128];

  const int tid = threadIdx.x;
  if (tid < 128) {
    const int m = min(m0 + tid, cnt - 1);
    srow[tid] = (GEMM == 1) ? slot_token[base + m] : (base + m);
  }
  __syncthreads();

  // staging roles
  const int arow = tid >> 1, akh = tid & 1;        // A: row, 32-k half
  const int rsrow = srow[arow];
  const float*  arowf = Xf + (size_t)rsrow * Kd;   // GEMM1
  const ushort* arowh = Hb + (size_t)rsrow * Kd;   // GEMM2
  const int bkb = tid >> 5, bnc = (tid & 31) * 4;  // B: k-block(8 rows), 4 cols

  // compute roles (4 waves, 2x2 of 64x64)
  const int wv = tid >> 6, ln = tid & 63;
  const int wm = (wv & 1) * 64, wn = (wv >> 1) * 64;
  const int lrow = ln & 15, kg = ln >> 4;

  f32x4 acc[4][4];
#pragma unroll
  for (int i = 0; i < 4; ++i)
#pragma unroll
    for (int j = 0; j < 4; ++j) acc[i][j] = (f32x4){0.f, 0.f, 0.f, 0.f};

  float4 va4[8];   // GEMM1 A staging (32 fp32)
  uint4  ha4[4];   // GEMM2 A staging (32 bf16)
  float4 wb4[8];   // B staging: 8 k-rows x 4 cols fp32

  // ---- prologue loads (tile 0) ----
#pragma unroll
  for (int j = 0; j < 8; ++j)
    wb4[j] = *(const float4*)(We + (size_t)(bkb * 8 + j) * Nd + n0 + bnc);
  if (GEMM == 1) {
#pragma unroll
    for (int i = 0; i < 8; ++i)
      va4[i] = ((const float4*)(arowf + akh * 32))[i];
  } else {
#pragma unroll
    for (int i = 0; i < 4; ++i)
      ha4[i] = ((const uint4*)(arowh + akh * 32))[i];
  }

  for (int k0 = 0; k0 < Kd; k0 += 64) {
    // ---- convert + LDS write (consumes staged regs) ----
    if (GEMM == 1) {
#pragma unroll
      for (int j = 0; j < 4; ++j) {
        float tv[8];
#pragma unroll
        for (int c = 0; c < 4; ++c) {
          tv[c]     = ((const float*)&va4[j * 2])[c];
          tv[4 + c] = ((const float*)&va4[j * 2 + 1])[c];
        }
        uint4 hq, lq;
        split8(tv, hq, lq);
        const int kb = akh * 4 + j;
        const int adr = arow * 64 + ((kb ^ (arow & 7)) << 3);
        *(uint4*)&Ah[adr] = hq;
        *(uint4*)&Al[adr] = lq;
      }
    } else {
#pragma unroll
      for (int j = 0; j < 4; ++j) {
        const int kb = akh * 4 + j;
        *(uint4*)&Ah[arow * 64 + ((kb ^ (arow & 7)) << 3)] = ha4[j];
      }
    }
#pragma unroll
    for (int c = 0; c < 4; ++c) {
      float tv[8];
#pragma unroll
      for (int j = 0; j < 8; ++j) tv[j] = ((const float*)&wb4[j])[c];
      uint4 hq, lq;
      split8(tv, hq, lq);
      const int rowb = bnc + c;
      const int adr = rowb * 64 + ((bkb ^ (rowb & 7)) << 3);
      *(uint4*)&Bh[adr] = hq;
      *(uint4*)&Bl[adr] = lq;
    }
    __syncthreads();

    // ---- T14: issue next tile's global loads before the MFMA cluster ----
    const int kn = k0 + 64;
    if (kn < Kd) {
#pragma unroll
      for (int j = 0; j < 8; ++j)
        wb4[j] = *(const float4*)(We + (size_t)(kn + bkb * 8 + j) * Nd + n0 + bnc);
      if (GEMM == 1) {
#pragma unroll
        for (int i = 0; i < 8; ++i)
          va4[i] = ((const float4*)(arowf + kn + akh * 32))[i];
      } else {
#pragma unroll
        for (int i = 0; i < 4; ++i)
          ha4[i] = ((const uint4*)(arowh + kn + akh * 32))[i];
      }
    }

    // ---- fragments + MFMA (2 sub-steps of K=32) ----
#pragma unroll
    for (int ks = 0; ks < 2; ++ks) {
      const int kb = ks * 4 + kg;
      bf16x8 af[4], alf[4], bhf[4], blf[4];
#pragma unroll
      for (int f = 0; f < 4; ++f) {
        const int ra = wm + f * 16 + lrow;
        const int ia = ra * 64 + ((kb ^ (ra & 7)) << 3);
        af[f] = *(const bf16x8*)&Ah[ia];
        if (GEMM == 1) alf[f] = *(const bf16x8*)&Al[ia];
        const int rb = wn + f * 16 + lrow;
        const int ib = rb * 64 + ((kb ^ (rb & 7)) << 3);
        bhf[f] = *(const bf16x8*)&Bh[ib];
        blf[f] = *(const bf16x8*)&Bl[ib];
      }
#pragma unroll
      for (int fm = 0; fm < 4; ++fm)
#pragma unroll
        for (int fn = 0; fn < 4; ++fn) {
          acc[fm][fn] = __builtin_amdgcn_mfma_f32_16x16x32_bf16(af[fm], bhf[fn], acc[fm][fn], 0, 0, 0);
          acc[fm][fn] = __builtin_amdgcn_mfma_f32_16x16x32_bf16(af[fm], blf[fn], acc[fm][fn], 0, 0, 0);
          if (GEMM == 1)
            acc[fm][fn] = __builtin_amdgcn_mfma_f32_16x16x32_bf16(alf[fm], bhf[fn], acc[fm][fn], 0, 0, 0);
        }
    }
    __syncthreads();  // fragment reads done before next overwrite
  }

  float bv[4];
#pragma unroll
  for (int fn = 0; fn < 4; ++fn)
    bv[fn] = bias[(size_t)e * Nd + n0 + wn + fn * 16 + lrow];

#pragma unroll
  for (int fm = 0; fm < 4; ++fm)
#pragma unroll
    for (int j = 0; j < 4; ++j) {
      const int m = m0 + wm + fm * 16 + kg * 4 + j;  // C/D: row=(lane>>4)*4+reg
      if (m < cnt) {
        if (GEMM == 1) {
          ushort* hr = Hout + (size_t)(base + m) * FFn + n0 + wn;
#pragma unroll
          for (int fn = 0; fn < 4; ++fn)
            hr[fn * 16 + lrow] = f2bf(fmaxf(acc[fm][fn][j] + bv[fn], 0.f));
        } else {
          const int t = slot_token[base + m];
          const float w = slot_w[base + m];
          float* yr = y + (size_t)t * Dn + n0 + wn;
#pragma unroll
          for (int fn = 0; fn < 4; ++fn)
            atomicAdd(yr + fn * 16 + lrow, w * (acc[fm][fn][j] + bv[fn]));
        }
      }
    }
}

// ------------------------------------- fp32/bf16 fallback (small-ws path) ---
__device__ inline void load8f(const float* p, float* v) {
  const float4 a = ((const float4*)p)[0];
  const float4 b = ((const float4*)p)[1];
  v[0] = a.x; v[1] = a.y; v[2] = a.z; v[3] = a.w;
  v[4] = b.x; v[5] = b.y; v[6] = b.z; v[7] = b.w;
}
__device__ inline void load8h(const __hip_bfloat16* p, float* v) {
  const uint4 r = *(const uint4*)p;
  const unsigned short* s = (const unsigned short*)&r;
#pragma unroll
  for (int j = 0; j < 8; ++j) v[j] = __uint_as_float(((unsigned)s[j]) << 16);
}

__global__ __launch_bounds__(256) void ffn1_kernel(
    const float* __restrict__ X, const float* __restrict__ W1,
    const float* __restrict__ b1, const int* __restrict__ slot_token,
    const int* __restrict__ meta, __hip_bfloat16* __restrict__ hmid) {
  const int e = blockIdx.z;
  const int cnt = meta[e];
  const int m0 = blockIdx.y * 64;
  if (m0 >= cnt) return;
  const int base = meta[8 + e];
  const int n0 = blockIdx.x * 64;
  __shared__ float As[32][64];
  __shared__ float Bs[32][64];
  const int tid = threadIdx.x;
  const int arow = tid >> 2, ak0 = (tid & 3) * 8;
  const int tok = slot_token[base + min(m0 + arow, cnt - 1)];
  const float* xrow = X + (size_t)tok * Dn;
  const int bkk = tid >> 3, bc0 = (tid & 7) * 8;
  const float* wrow = W1 + (size_t)e * Dn * FFn + n0;
  const int tm = (tid >> 4) << 2, tn = (tid & 15) << 2;
  float acc[4][4] = {};
  for (int k0 = 0; k0 < Dn; k0 += 32) {
    float av[8], bv[8];
    load8f(xrow + k0 + ak0, av);
    load8f(wrow + (size_t)(k0 + bkk) * FFn + bc0, bv);
    __syncthreads();
#pragma unroll
    for (int u = 0; u < 8; ++u) As[ak0 + u][arow] = av[u];
#pragma unroll
    for (int u = 0; u < 8; ++u) Bs[bkk][bc0 + u] = bv[u];
    __syncthreads();
#pragma unroll
    for (int kk = 0; kk < 32; ++kk) {
      float a[4], b[4];
#pragma unroll
      for (int i = 0; i < 4; ++i) a[i] = As[kk][tm + i];
#pragma unroll
      for (int j = 0; j < 4; ++j) b[j] = Bs[kk][tn + j];
#pragma unroll
      for (int i = 0; i < 4; ++i)
#pragma unroll
        for (int j = 0; j < 4; ++j) acc[i][j] = fmaf(a[i], b[j], acc[i][j]);
    }
  }
  const float* bb = b1 + (size_t)e * FFn + n0;
#pragma unroll
  for (int i = 0; i < 4; ++i) {
    const int m = m0 + tm + i;
    if (m < cnt) {
      __hip_bfloat16* hr = hmid + (size_t)(base + m) * FFn + n0 + tn;
#pragma unroll
      for (int j = 0; j < 4; ++j)
        hr[j] = __hip_bfloat16(fmaxf(acc[i][j] + bb[tn + j], 0.f));
    }
  }
}

__global__ __launch_bounds__(256) void ffn2_kernel(
    const __hip_bfloat16* __restrict__ hmid, const float* __restrict__ W2,
    const float* __restrict__ b2, const int* __restrict__ slot_token,
    const float* __restrict__ slot_w, const int* __restrict__ meta,
    float* __restrict__ y) {
  const int e = blockIdx.z;
  const int cnt = meta[e];
  const int m0 = blockIdx.y * 64;
  if (m0 >= cnt) return;
  const int base = meta[8 + e];
  const int n0 = blockIdx.x * 64;
  __shared__ float As[32][64];
  __shared__ float Bs[32][64];
  const int tid = threadIdx.x;
  const int arow = tid >> 2, ak0 = (tid & 3) * 8;
  const __hip_bfloat16* hrow = hmid + (size_t)(base + min(m0 + arow, cnt - 1)) * FFn;
  const int bkk = tid >> 3, bc0 = (tid & 7) * 8;
  const float* wrow = W2 + (size_t)e * FFn * Dn + n0;
  const int tm = (tid >> 4) << 2, tn = (tid & 15) << 2;
  float acc[4][4] = {};
  for (int k0 = 0; k0 < FFn; k0 += 32) {
    float av[8], bv[8];
    load8h(hrow + k0 + ak0, av);
    load8f(wrow + (size_t)(k0 + bkk) * Dn + bc0, bv);
    __syncthreads();
#pragma unroll
    for (int u = 0; u < 8; ++u) As[ak0 + u][arow] = av[u];
#pragma unroll
    for (int u = 0; u < 8; ++u) Bs[bkk][bc0 + u] = bv[u];
    __syncthreads();
#pragma unroll
    for (int kk = 0; kk < 32; ++kk) {
      float a[4], b[4];
#pragma unroll
      for (int i = 0; i < 4; ++i) a[i] = As[kk][tm + i];
#pragma unroll
      for (int j = 0; j < 4; ++j) b[j] = Bs[kk][tn + j];
#pragma unroll
      for (int i = 0; i < 4; ++i)
#pragma unroll
        for (int j = 0; j < 4; ++j) acc[i][j] = fmaf(a[i], b[j], acc[i][j]);
    }
  }
  const float* bb = b2 + (size_t)e * Dn + n0;
#pragma unroll
  for (int i = 0; i < 4; ++i) {
    const int m = m0 + tm + i;
    if (m < cnt) {
      const int t = slot_token[base + m];
      const float w = slot_w[base + m];
      float* yr = y + (size_t)t * Dn + n0 + tn;
#pragma unroll
      for (int j = 0; j < 4; ++j)
        atomicAdd(&yr[j], w * (acc[i][j] + bb[tn + j]));
    }
  }
}

// ---------------------------------------------------------------- launch ----
extern "C" void kernel_launch(void* const* d_in, const int* in_sizes, int n_in,
                              void* d_out, int out_size, void* d_ws, size_t ws_size,
                              hipStream_t stream) {
  const float* h  = (const float*)d_in[0];
  const float* gw = (const float*)d_in[1];
  const float* gb = (const float*)d_in[2];
  const float* W1 = (const float*)d_in[3];
  const float* b1 = (const float*)d_in[4];
  const float* W2 = (const float*)d_in[5];
  const float* b2 = (const float*)d_in[6];
  float* y = (float*)d_out;

  char* ws = (char*)d_ws;
  size_t off = 0;
  auto carve = [&](size_t bytes) -> char* {
    char* p = ws + off;
    off = (off + bytes + 255) & ~(size_t)255;
    return p;
  };
  int*    tidx       = (int*)carve((size_t)Tn * 2 * 4);
  float*  tprob      = (float*)carve((size_t)Tn * 2 * 4);
  int*    slot_token = (int*)carve((size_t)MAXROWS * 4);
  float*  slot_w     = (float*)carve((size_t)MAXROWS * 4);
  int*    meta       = (int*)carve(256);
  const size_t small_end = off;

  hipMemsetAsync(d_out, 0, (size_t)Tn * Dn * sizeof(float), stream);
  gate_kernel<<<Tn / 4, 256, 0, stream>>>(h, gw, gb, tidx, tprob);
  route_kernel<<<1, 1024, 0, stream>>>(tidx, tprob, slot_token, slot_w, meta);

  // ---- MFMA path: ws needs only H (bf16) -> 134.5 MB, proven to fit ----
  const size_t hplane = (size_t)MAXROWS * FFn * 2;
  const size_t need_mfma = small_end + hplane;

  if (ws_size >= need_mfma) {
    ushort* H = (ushort*)carve(hplane);
    const dim3 g1(FFn / 128, (2 * CAPn + 127) / 128, En);  // (32, 40, 8)
    const dim3 g2(Dn / 128, (2 * CAPn + 127) / 128, En);   // (8, 40, 8)
    mfma_ffn<1><<<g1, 256, 0, stream>>>(h, nullptr, W1, b1, slot_token,
                                        slot_w, meta, H, nullptr);
    mfma_ffn<2><<<g2, 256, 0, stream>>>(nullptr, H, W2, b2, slot_token,
                                        slot_w, meta, nullptr, y);
    return;
  }

  // ---- fallback (proven-pass round 4) ----
  __hip_bfloat16* hmid = (__hip_bfloat16*)(ws + small_end);
  const dim3 f1(FFn / 64, (2 * CAPn + 63) / 64, En);
  const dim3 f2(Dn / 64, (2 * CAPn + 63) / 64, En);
  ffn1_kernel<<<f1, 256, 0, stream>>>(h, W1, b1, slot_token, meta, hmid);
  ffn2_kernel<<<f2, 256, 0, stream>>>(hmid, W2, b2, slot_token, slot_w, meta, y);
}

// Round 10
// 1333.331 us; speedup vs baseline: 1.0124x; 1.0124x over previous
//
#include <hip/hip_runtime.h>
#include <hip/hip_bf16.h>

#define Tn   8192
#define Dn   1024
#define FFn  4096
#define En   8
#define CAPn 2560
#define MAXROWS 16384  // <= K*T total kept slots

typedef __attribute__((ext_vector_type(8))) short bf16x8;
typedef __attribute__((ext_vector_type(4))) float f32x4;

__device__ inline ushort f2bf(float f) {            // RNE fp32->bf16 bits
  unsigned u = __float_as_uint(f);
  return (ushort)((u + 0x7fff + ((u >> 16) & 1)) >> 16);
}
__device__ inline float bf2f(ushort b) { return __uint_as_float(((unsigned)b) << 16); }

// split 8 fp32 -> hi (truncated) + lo bf16 planes; hi+lo exact to ~2^-17
__device__ inline void split8(const float* v, uint4& hq, uint4& lq) {
  union U8 { ushort u[8]; uint4 q; } H, L;
#pragma unroll
  for (int j = 0; j < 8; ++j) {
    const unsigned u = __float_as_uint(v[j]);
    H.u[j] = (ushort)(u >> 16);
    L.u[j] = (ushort)(__float_as_uint(v[j] - __uint_as_float(u & 0xffff0000u)) >> 16);
  }
  hq = H.q;
  lq = L.q;
}

// ---------------------------------------------------------------- gating ----
__global__ __launch_bounds__(256) void gate_kernel(
    const float* __restrict__ x, const float* __restrict__ gw,
    const float* __restrict__ gb, int* __restrict__ tidx,
    float* __restrict__ tprob) {
  __shared__ float sgw[En * Dn];  // 32 KB
  for (int i = threadIdx.x; i < En * Dn / 4; i += 256)
    ((float4*)sgw)[i] = ((const float4*)gw)[i];
  __syncthreads();
  const int wave = threadIdx.x >> 6, lane = threadIdx.x & 63;
  const int t = blockIdx.x * 4 + wave;
  float acc[En];
#pragma unroll
  for (int e = 0; e < En; ++e) acc[e] = 0.f;
  const float4* xr = (const float4*)(x + (size_t)t * Dn);
#pragma unroll
  for (int it = 0; it < Dn / 4 / 64; ++it) {
    const float4 xv = xr[it * 64 + lane];
#pragma unroll
    for (int e = 0; e < En; ++e) {
      const float4 wv = ((const float4*)(sgw + e * Dn))[it * 64 + lane];
      acc[e] += xv.x * wv.x + xv.y * wv.y + xv.z * wv.z + xv.w * wv.w;
    }
  }
#pragma unroll
  for (int e = 0; e < En; ++e)
#pragma unroll
    for (int off = 32; off; off >>= 1) acc[e] += __shfl_xor(acc[e], off, 64);
  if (lane == 0) {
    float lg[En], mx = -1e30f;
#pragma unroll
    for (int e = 0; e < En; ++e) { lg[e] = acc[e] + gb[e]; mx = fmaxf(mx, lg[e]); }
    float ex[En], s = 0.f;
#pragma unroll
    for (int e = 0; e < En; ++e) { ex[e] = expf(lg[e] - mx); s += ex[e]; }
    int i0 = 0;
#pragma unroll
    for (int e = 1; e < En; ++e) if (ex[e] > ex[i0]) i0 = e;
    int i1 = (i0 == 0) ? 1 : 0;
#pragma unroll
    for (int e = 0; e < En; ++e) if (e != i0 && ex[e] > ex[i1]) i1 = e;
    const float inv = 1.f / s;
    tidx[t * 2 + 0] = i0;  tidx[t * 2 + 1] = i1;
    tprob[t * 2 + 0] = ex[i0] * inv;  tprob[t * 2 + 1] = ex[i1] * inv;
  }
}

// ------------------------------------------------------- routing (1 block) --
__global__ __launch_bounds__(1024) void route_kernel(
    const int* __restrict__ tidx, const float* __restrict__ tprob,
    int* __restrict__ slot_token, float* __restrict__ slot_w,
    int* __restrict__ meta) {
  __shared__ int sc[1024][16];  // 64 KB
  const int tid = threadIdx.x;
  int cnt[16];
#pragma unroll
  for (int j = 0; j < 16; ++j) cnt[j] = 0;
  int eb[8][2];
#pragma unroll
  for (int i = 0; i < 8; ++i) {
    const int t = tid * 8 + i;
    eb[i][0] = tidx[t * 2 + 0];
    eb[i][1] = tidx[t * 2 + 1];
#pragma unroll
    for (int e = 0; e < 8; ++e) {
      cnt[e]     += (eb[i][0] == e);
      cnt[8 + e] += (eb[i][1] == e);
    }
  }
  int own[16];
#pragma unroll
  for (int j = 0; j < 16; ++j) { own[j] = cnt[j]; sc[tid][j] = cnt[j]; }
  __syncthreads();
  for (int off = 1; off < 1024; off <<= 1) {
    int nb[16];
    if (tid >= off) {
#pragma unroll
      for (int j = 0; j < 16; ++j) nb[j] = sc[tid - off][j];
    } else {
#pragma unroll
      for (int j = 0; j < 16; ++j) nb[j] = 0;
    }
    __syncthreads();
#pragma unroll
    for (int j = 0; j < 16; ++j) sc[tid][j] += nb[j];
    __syncthreads();
  }
  int tot[16], exc[16];
#pragma unroll
  for (int j = 0; j < 16; ++j) {
    tot[j] = sc[1023][j];
    exc[j] = sc[tid][j] - own[j];
  }
  __syncthreads();
  if (tid == 0) {
    int b = 0;
#pragma unroll
    for (int e = 0; e < 8; ++e) {
      const int c0 = min(tot[e], CAPn);
      const int c1 = min(tot[8 + e], CAPn);
      sc[0][e] = b;
      sc[1][e] = c0;
      meta[e] = c0 + c1;
      meta[8 + e] = b;
      b += c0 + c1;
    }
  }
  __syncthreads();
  int pos[16];
#pragma unroll
  for (int j = 0; j < 16; ++j) pos[j] = exc[j];
#pragma unroll
  for (int i = 0; i < 8; ++i) {
    const int t = tid * 8 + i;
#pragma unroll
    for (int c = 0; c < 2; ++c) {
      const int e = eb[i][c];
      const int jt = c * 8 + e;
      int p = 0;
#pragma unroll
      for (int j = 0; j < 16; ++j) p = (j == jt) ? pos[j] : p;
#pragma unroll
      for (int j = 0; j < 16; ++j) pos[j] += (j == jt) ? 1 : 0;
      if (p < CAPn) {
        const int slot = sc[0][e] + ((c == 1) ? sc[1][e] : 0) + p;
        slot_token[slot] = t;
        slot_w[slot] = tprob[t * 2 + c];
      }
    }
  }
}

// --------------------------------------------- split-bf16 MFMA FFN GEMMs ----
// GEMM==1: H[slot] = relu(X[token[slot]] @ W1[e] + b1[e])   (bf16 out)
// GEMM==2: y[token] += w * (H[slot] @ W2[e] + b2[e])         (fp32 atomics)
// Round-5 proven tile/swizzle (BK=32, 0 bank conflicts) + LDS double-buffer:
// per iter {issue loads k+1} -> {frag reads buf p + MFMA} -> {convert+write
// buf p^1} -> {1 barrier}. DS in-order issue => MFMA overlaps load latency.
#define PL (128 * 32)  // ushorts per plane
template <int GEMM>
__global__ __launch_bounds__(256, 2) void mfma_ffn(
    const float* __restrict__ Xf, const ushort* __restrict__ Hb,
    const float* __restrict__ Wg, const float* __restrict__ bias,
    const int* __restrict__ slot_token, const float* __restrict__ slot_w,
    const int* __restrict__ meta, ushort* __restrict__ Hout,
    float* __restrict__ y) {
  constexpr int Kd = (GEMM == 1) ? Dn : FFn;
  constexpr int Nd = (GEMM == 1) ? FFn : Dn;
  const int e = blockIdx.z;
  const int cnt = meta[e];
  const int m0 = blockIdx.y * 128;
  if (m0 >= cnt) return;
  const int base = meta[8 + e];
  const int n0 = blockIdx.x * 128;
  const float* We = Wg + (size_t)e * Kd * Nd;

  __shared__ ushort Ah[2 * PL];
  __shared__ ushort Al[2 * PL];   // dead (stripped) for GEMM2
  __shared__ ushort Bh[2 * PL];
  __shared__ ushort Bl[2 * PL];
  __shared__ int srow[128];

  const int tid = threadIdx.x;
  if (tid < 128) {
    const int m = min(m0 + tid, cnt - 1);
    srow[tid] = (GEMM == 1) ? slot_token[base + m] : (base + m);
  }
  __syncthreads();

  // staging roles (round-5 proven)
  const int sm = tid >> 1, skh = tid & 1;          // A: row, 16-k half
  const int rsrow = srow[sm];
  const float*  arowf = Xf + (size_t)rsrow * Kd;   // GEMM1
  const ushort* arowh = Hb + (size_t)rsrow * Kd;   // GEMM2
  const int aswz = (sm >> 1) & 3;
  const int ab0 = ((skh * 2 + 0) ^ aswz) << 3;
  const int ab1 = ((skh * 2 + 1) ^ aswz) << 3;
  const int bn = tid & 127, bkh = tid >> 7;        // B: col(n)->row, 16-k half
  const int bswz = (bn >> 1) & 3;
  const int bb0 = ((bkh * 2 + 0) ^ bswz) << 3;
  const int bb1 = ((bkh * 2 + 1) ^ bswz) << 3;

  // compute roles (4 waves, 2x2 of 64x64)
  const int wv = tid >> 6, ln = tid & 63;
  const int wm = (wv & 1) * 64, wn = (wv >> 1) * 64;
  const int lrow = ln & 15, kg = ln >> 4;

  f32x4 acc[4][4];
#pragma unroll
  for (int i = 0; i < 4; ++i)
#pragma unroll
    for (int j = 0; j < 4; ++j) acc[i][j] = (f32x4){0.f, 0.f, 0.f, 0.f};

  float va[16];   // GEMM1 A staging (16 fp32)
  uint4 ha[2];    // GEMM2 A staging (16 bf16)
  float vb[16];   // B staging (16 fp32, k-strided)

  // ---- load tile 0 ----
#pragma unroll
  for (int j = 0; j < 16; ++j)
    vb[j] = We[(size_t)(bkh * 16 + j) * Nd + n0 + bn];
  if (GEMM == 1) {
#pragma unroll
    for (int i = 0; i < 4; ++i) {
      const float4 f = ((const float4*)(arowf + skh * 16))[i];
      va[i * 4 + 0] = f.x; va[i * 4 + 1] = f.y;
      va[i * 4 + 2] = f.z; va[i * 4 + 3] = f.w;
    }
  } else {
    ha[0] = ((const uint4*)(arowh + skh * 16))[0];
    ha[1] = ((const uint4*)(arowh + skh * 16))[1];
  }
  // ---- convert + write buf 0 ----
  {
    if (GEMM == 1) {
      uint4 hq, lq;
      split8(va, hq, lq);
      *(uint4*)&Ah[sm * 32 + ab0] = hq;
      *(uint4*)&Al[sm * 32 + ab0] = lq;
      split8(va + 8, hq, lq);
      *(uint4*)&Ah[sm * 32 + ab1] = hq;
      *(uint4*)&Al[sm * 32 + ab1] = lq;
    } else {
      *(uint4*)&Ah[sm * 32 + ab0] = ha[0];
      *(uint4*)&Ah[sm * 32 + ab1] = ha[1];
    }
    uint4 hq, lq;
    split8(vb, hq, lq);
    *(uint4*)&Bh[bn * 32 + bb0] = hq;
    *(uint4*)&Bl[bn * 32 + bb0] = lq;
    split8(vb + 8, hq, lq);
    *(uint4*)&Bh[bn * 32 + bb1] = hq;
    *(uint4*)&Bl[bn * 32 + bb1] = lq;
  }
  __syncthreads();

  int p = 0;
  for (int k0 = 0; k0 < Kd; k0 += 32) {
    const bool next = (k0 + 32 < Kd);
    // ---- T14: issue next tile's global loads first (no LDS deps) ----
    if (next) {
      const int kn = k0 + 32;
#pragma unroll
      for (int j = 0; j < 16; ++j)
        vb[j] = We[(size_t)(kn + bkh * 16 + j) * Nd + n0 + bn];
      if (GEMM == 1) {
#pragma unroll
        for (int i = 0; i < 4; ++i) {
          const float4 f = ((const float4*)(arowf + kn + skh * 16))[i];
          va[i * 4 + 0] = f.x; va[i * 4 + 1] = f.y;
          va[i * 4 + 2] = f.z; va[i * 4 + 3] = f.w;
        }
      } else {
        ha[0] = ((const uint4*)(arowh + kn + skh * 16))[0];
        ha[1] = ((const uint4*)(arowh + kn + skh * 16))[1];
      }
    }
    // ---- fragment reads (buf p) + MFMA ----
    {
      const ushort* Ahp = Ah + p * PL;
      const ushort* Alp = Al + p * PL;
      const ushort* Bhp = Bh + p * PL;
      const ushort* Blp = Bl + p * PL;
      bf16x8 af[4], alf[4], bhf[4], blf[4];
#pragma unroll
      for (int f = 0; f < 4; ++f) {
        const int ra = wm + f * 16 + lrow;
        const int ia = ra * 32 + ((kg ^ ((ra >> 1) & 3)) << 3);
        af[f] = *(const bf16x8*)&Ahp[ia];
        if (GEMM == 1) alf[f] = *(const bf16x8*)&Alp[ia];
        const int rb = wn + f * 16 + lrow;
        const int ib = rb * 32 + ((kg ^ ((rb >> 1) & 3)) << 3);
        bhf[f] = *(const bf16x8*)&Bhp[ib];
        blf[f] = *(const bf16x8*)&Blp[ib];
      }
#pragma unroll
      for (int fm = 0; fm < 4; ++fm)
#pragma unroll
        for (int fn = 0; fn < 4; ++fn) {
          acc[fm][fn] = __builtin_amdgcn_mfma_f32_16x16x32_bf16(af[fm], bhf[fn], acc[fm][fn], 0, 0, 0);
          acc[fm][fn] = __builtin_amdgcn_mfma_f32_16x16x32_bf16(af[fm], blf[fn], acc[fm][fn], 0, 0, 0);
          if (GEMM == 1)
            acc[fm][fn] = __builtin_amdgcn_mfma_f32_16x16x32_bf16(alf[fm], bhf[fn], acc[fm][fn], 0, 0, 0);
        }
    }
    // ---- convert + write buf p^1 (waits on loads via vmcnt) ----
    if (next) {
      ushort* Ahq = Ah + (p ^ 1) * PL;
      ushort* Alq = Al + (p ^ 1) * PL;
      ushort* Bhq = Bh + (p ^ 1) * PL;
      ushort* Blq = Bl + (p ^ 1) * PL;
      if (GEMM == 1) {
        uint4 hq, lq;
        split8(va, hq, lq);
        *(uint4*)&Ahq[sm * 32 + ab0] = hq;
        *(uint4*)&Alq[sm * 32 + ab0] = lq;
        split8(va + 8, hq, lq);
        *(uint4*)&Ahq[sm * 32 + ab1] = hq;
        *(uint4*)&Alq[sm * 32 + ab1] = lq;
      } else {
        *(uint4*)&Ahq[sm * 32 + ab0] = ha[0];
        *(uint4*)&Ahq[sm * 32 + ab1] = ha[1];
      }
      uint4 hq, lq;
      split8(vb, hq, lq);
      *(uint4*)&Bhq[bn * 32 + bb0] = hq;
      *(uint4*)&Blq[bn * 32 + bb0] = lq;
      split8(vb + 8, hq, lq);
      *(uint4*)&Bhq[bn * 32 + bb1] = hq;
      *(uint4*)&Blq[bn * 32 + bb1] = lq;
      __syncthreads();
      p ^= 1;
    }
  }

  float bv[4];
#pragma unroll
  for (int fn = 0; fn < 4; ++fn)
    bv[fn] = bias[(size_t)e * Nd + n0 + wn + fn * 16 + lrow];

#pragma unroll
  for (int fm = 0; fm < 4; ++fm)
#pragma unroll
    for (int j = 0; j < 4; ++j) {
      const int m = m0 + wm + fm * 16 + kg * 4 + j;  // C/D: row=(lane>>4)*4+reg
      if (m < cnt) {
        if (GEMM == 1) {
          ushort* hr = Hout + (size_t)(base + m) * FFn + n0 + wn;
#pragma unroll
          for (int fn = 0; fn < 4; ++fn)
            hr[fn * 16 + lrow] = f2bf(fmaxf(acc[fm][fn][j] + bv[fn], 0.f));
        } else {
          const int t = slot_token[base + m];
          const float w = slot_w[base + m];
          float* yr = y + (size_t)t * Dn + n0 + wn;
#pragma unroll
          for (int fn = 0; fn < 4; ++fn)
            atomicAdd(yr + fn * 16 + lrow, w * (acc[fm][fn][j] + bv[fn]));
        }
      }
    }
}

// ------------------------------------- fp32/bf16 fallback (small-ws path) ---
__device__ inline void load8f(const float* p, float* v) {
  const float4 a = ((const float4*)p)[0];
  const float4 b = ((const float4*)p)[1];
  v[0] = a.x; v[1] = a.y; v[2] = a.z; v[3] = a.w;
  v[4] = b.x; v[5] = b.y; v[6] = b.z; v[7] = b.w;
}
__device__ inline void load8h(const __hip_bfloat16* p, float* v) {
  const uint4 r = *(const uint4*)p;
  const unsigned short* s = (const unsigned short*)&r;
#pragma unroll
  for (int j = 0; j < 8; ++j) v[j] = __uint_as_float(((unsigned)s[j]) << 16);
}

__global__ __launch_bounds__(256) void ffn1_kernel(
    const float* __restrict__ X, const float* __restrict__ W1,
    const float* __restrict__ b1, const int* __restrict__ slot_token,
    const int* __restrict__ meta, __hip_bfloat16* __restrict__ hmid) {
  const int e = blockIdx.z;
  const int cnt = meta[e];
  const int m0 = blockIdx.y * 64;
  if (m0 >= cnt) return;
  const int base = meta[8 + e];
  const int n0 = blockIdx.x * 64;
  __shared__ float As[32][64];
  __shared__ float Bs[32][64];
  const int tid = threadIdx.x;
  const int arow = tid >> 2, ak0 = (tid & 3) * 8;
  const int tok = slot_token[base + min(m0 + arow, cnt - 1)];
  const float* xrow = X + (size_t)tok * Dn;
  const int bkk = tid >> 3, bc0 = (tid & 7) * 8;
  const float* wrow = W1 + (size_t)e * Dn * FFn + n0;
  const int tm = (tid >> 4) << 2, tn = (tid & 15) << 2;
  float acc[4][4] = {};
  for (int k0 = 0; k0 < Dn; k0 += 32) {
    float av[8], bv[8];
    load8f(xrow + k0 + ak0, av);
    load8f(wrow + (size_t)(k0 + bkk) * FFn + bc0, bv);
    __syncthreads();
#pragma unroll
    for (int u = 0; u < 8; ++u) As[ak0 + u][arow] = av[u];
#pragma unroll
    for (int u = 0; u < 8; ++u) Bs[bkk][bc0 + u] = bv[u];
    __syncthreads();
#pragma unroll
    for (int kk = 0; kk < 32; ++kk) {
      float a[4], b[4];
#pragma unroll
      for (int i = 0; i < 4; ++i) a[i] = As[kk][tm + i];
#pragma unroll
      for (int j = 0; j < 4; ++j) b[j] = Bs[kk][tn + j];
#pragma unroll
      for (int i = 0; i < 4; ++i)
#pragma unroll
        for (int j = 0; j < 4; ++j) acc[i][j] = fmaf(a[i], b[j], acc[i][j]);
    }
  }
  const float* bb = b1 + (size_t)e * FFn + n0;
#pragma unroll
  for (int i = 0; i < 4; ++i) {
    const int m = m0 + tm + i;
    if (m < cnt) {
      __hip_bfloat16* hr = hmid + (size_t)(base + m) * FFn + n0 + tn;
#pragma unroll
      for (int j = 0; j < 4; ++j)
        hr[j] = __hip_bfloat16(fmaxf(acc[i][j] + bb[tn + j], 0.f));
    }
  }
}

__global__ __launch_bounds__(256) void ffn2_kernel(
    const __hip_bfloat16* __restrict__ hmid, const float* __restrict__ W2,
    const float* __restrict__ b2, const int* __restrict__ slot_token,
    const float* __restrict__ slot_w, const int* __restrict__ meta,
    float* __restrict__ y) {
  const int e = blockIdx.z;
  const int cnt = meta[e];
  const int m0 = blockIdx.y * 64;
  if (m0 >= cnt) return;
  const int base = meta[8 + e];
  const int n0 = blockIdx.x * 64;
  __shared__ float As[32][64];
  __shared__ float Bs[32][64];
  const int tid = threadIdx.x;
  const int arow = tid >> 2, ak0 = (tid & 3) * 8;
  const __hip_bfloat16* hrow = hmid + (size_t)(base + min(m0 + arow, cnt - 1)) * FFn;
  const int bkk = tid >> 3, bc0 = (tid & 7) * 8;
  const float* wrow = W2 + (size_t)e * FFn * Dn + n0;
  const int tm = (tid >> 4) << 2, tn = (tid & 15) << 2;
  float acc[4][4] = {};
  for (int k0 = 0; k0 < FFn; k0 += 32) {
    float av[8], bv[8];
    load8h(hrow + k0 + ak0, av);
    load8f(wrow + (size_t)(k0 + bkk) * Dn + bc0, bv);
    __syncthreads();
#pragma unroll
    for (int u = 0; u < 8; ++u) As[ak0 + u][arow] = av[u];
#pragma unroll
    for (int u = 0; u < 8; ++u) Bs[bkk][bc0 + u] = bv[u];
    __syncthreads();
#pragma unroll
    for (int kk = 0; kk < 32; ++kk) {
      float a[4], b[4];
#pragma unroll
      for (int i = 0; i < 4; ++i) a[i] = As[kk][tm + i];
#pragma unroll
      for (int j = 0; j < 4; ++j) b[j] = Bs[kk][tn + j];
#pragma unroll
      for (int i = 0; i < 4; ++i)
#pragma unroll
        for (int j = 0; j < 4; ++j) acc[i][j] = fmaf(a[i], b[j], acc[i][j]);
    }
  }
  const float* bb = b2 + (size_t)e * Dn + n0;
#pragma unroll
  for (int i = 0; i < 4; ++i) {
    const int m = m0 + tm + i;
    if (m < cnt) {
      const int t = slot_token[base + m];
      const float w = slot_w[base + m];
      float* yr = y + (size_t)t * Dn + n0 + tn;
#pragma unroll
      for (int j = 0; j < 4; ++j)
        atomicAdd(&yr[j], w * (acc[i][j] + bb[tn + j]));
    }
  }
}

// ---------------------------------------------------------------- launch ----
extern "C" void kernel_launch(void* const* d_in, const int* in_sizes, int n_in,
                              void* d_out, int out_size, void* d_ws, size_t ws_size,
                              hipStream_t stream) {
  const float* h  = (const float*)d_in[0];
  const float* gw = (const float*)d_in[1];
  const float* gb = (const float*)d_in[2];
  const float* W1 = (const float*)d_in[3];
  const float* b1 = (const float*)d_in[4];
  const float* W2 = (const float*)d_in[5];
  const float* b2 = (const float*)d_in[6];
  float* y = (float*)d_out;

  char* ws = (char*)d_ws;
  size_t off = 0;
  auto carve = [&](size_t bytes) -> char* {
    char* p = ws + off;
    off = (off + bytes + 255) & ~(size_t)255;
    return p;
  };
  int*    tidx       = (int*)carve((size_t)Tn * 2 * 4);
  float*  tprob      = (float*)carve((size_t)Tn * 2 * 4);
  int*    slot_token = (int*)carve((size_t)MAXROWS * 4);
  float*  slot_w     = (float*)carve((size_t)MAXROWS * 4);
  int*    meta       = (int*)carve(256);
  const size_t small_end = off;

  hipMemsetAsync(d_out, 0, (size_t)Tn * Dn * sizeof(float), stream);
  gate_kernel<<<Tn / 4, 256, 0, stream>>>(h, gw, gb, tidx, tprob);
  route_kernel<<<1, 1024, 0, stream>>>(tidx, tprob, slot_token, slot_w, meta);

  // ---- MFMA path: ws needs only H (bf16) -> 134.5 MB, proven to fit ----
  const size_t hplane = (size_t)MAXROWS * FFn * 2;
  const size_t need_mfma = small_end + hplane;

  if (ws_size >= need_mfma) {
    ushort* H = (ushort*)carve(hplane);
    const dim3 g1(FFn / 128, (2 * CAPn + 127) / 128, En);  // (32, 40, 8)
    const dim3 g2(Dn / 128, (2 * CAPn + 127) / 128, En);   // (8, 40, 8)
    mfma_ffn<1><<<g1, 256, 0, stream>>>(h, nullptr, W1, b1, slot_token,
                                        slot_w, meta, H, nullptr);
    mfma_ffn<2><<<g2, 256, 0, stream>>>(nullptr, H, W2, b2, slot_token,
                                        slot_w, meta, nullptr, y);
    return;
  }

  // ---- fallback (proven-pass round 4) ----
  __hip_bfloat16* hmid = (__hip_bfloat16*)(ws + small_end);
  const dim3 f1(FFn / 64, (2 * CAPn + 63) / 64, En);
  const dim3 f2(Dn / 64, (2 * CAPn + 63) / 64, En);
  ffn1_kernel<<<f1, 256, 0, stream>>>(h, W1, b1, slot_token, meta, hmid);
  ffn2_kernel<<<f2, 256, 0, stream>>>(hmid, W2, b2, slot_token, slot_w, meta, y);
}